// Round 16
// baseline (380.203 us; speedup 1.0000x reference)
//
#include <hip/hip_runtime.h>
#include <cstdint>
#include <cstddef>

#define D_MODEL 1024
#define D_FF    2048
#define N_EXP   8
#define NTOK    4096          // B*S
#define NASSIGN (NTOK * 2)    // top-2
#define MAXTILE 72            // ctrl-buffer layout (256-row tiles use <= 40)

typedef __bf16 bf16_t;
typedef bf16_t bf16x8 __attribute__((ext_vector_type(8)));
typedef float  f32x4  __attribute__((ext_vector_type(4)));

typedef __attribute__((address_space(3))) void       lds_void;
typedef const __attribute__((address_space(1))) void gl_void;

__device__ __forceinline__ unsigned short f2b(float f) {
  union { float f; unsigned u; } v; v.f = f;
  unsigned u = v.u;
  unsigned r = (u + 0x7FFFu + ((u >> 16) & 1u)) >> 16;  // RNE
  return (unsigned short)r;
}
__device__ __forceinline__ float b2f(unsigned short b) {
  union { unsigned u; float f; } v; v.u = ((unsigned)b) << 16; return v.f;
}
__device__ __forceinline__ unsigned cvt_pk_bf16(float lo, float hi) {
  unsigned r;
  asm("v_cvt_pk_bf16_f32 %0, %1, %2" : "=v"(r) : "v"(lo), "v"(hi));
  return r;   // low16 = bf16(lo), high16 = bf16(hi)
}

// ---------------- Prep: w1/w2 transpose (128x64, global_load_lds) | router ----------
// R12: prep was latency-bound; R11's reg-ILP was sunk by the compiler (VGPR stayed
// 36).  global_load_lds is fire-and-forget -> 8x16B/thread in flight guaranteed.
// fp32 tile [128][64] in LDS, source pre-swizzled pos^(row&15); read-back b32 with
// s4-staggered j (<=2-way conflicts, free); v_cvt_pk_bf16_f32 pack; 256B stores.
__device__ __forceinline__ void transpose_tile_glds(
    const float* __restrict__ ein, unsigned short* __restrict__ eout,
    int R /*out stride*/, int C /*in cols*/, int r0, int c0,
    unsigned* T /*32KB*/, int tid)
{
  const int l = tid & 63;
  const int w = tid >> 6;        // wave 0..3
  const int p  = l & 15;         // 16B chunk within row
  const int lr = l >> 4;         // row within load group

  #pragma unroll
  for (int n = 0; n < 8; ++n) {
    int row = (n * 4 + w) * 4 + lr;            // 0..127
    const float* src = ein + (size_t)(r0 + row) * C + c0 + (((p ^ (row & 15)) << 2));
    __builtin_amdgcn_global_load_lds((gl_void*)src,
        (lds_void*)((char*)T + (n * 4 + w) * 1024), 16, 0, 0);
  }
  __syncthreads();   // drains vmcnt, publishes LDS

  const int c  = tid >> 2;       // 0..63 : output row (input col)
  const int s4 = tid & 3;        // 32-row segment along r
  const int pc = c >> 2, cl = c & 3;
  unsigned ow[16];
  #pragma unroll
  for (int j2 = 0; j2 < 16; ++j2) {
    int j  = (j2 + 4 * s4) & 15;               // stagger per s4: bank spread
    int r  = s4 * 32 + 2 * j;
    float lo, hi;
    { unsigned u = T[r * 64 + ((pc ^ (r & 15)) << 2) + cl];
      union { unsigned u; float f; } v; v.u = u; lo = v.f; }
    { int r1 = r + 1;
      unsigned u = T[r1 * 64 + ((pc ^ (r1 & 15)) << 2) + cl];
      union { unsigned u; float f; } v; v.u = u; hi = v.f; }
    ow[j] = cvt_pk_bf16(lo, hi);
  }
  uint4* dst = (uint4*)(eout + (size_t)(c0 + c) * R + r0 + s4 * 32);
  dst[0] = *(uint4*)&ow[0];
  dst[1] = *(uint4*)&ow[4];
  dst[2] = *(uint4*)&ow[8];
  dst[3] = *(uint4*)&ow[12];
}

__global__ __launch_bounds__(256) void prep_k(
    const float* __restrict__ x, const float* __restrict__ gw,
    const float* __restrict__ w1, const float* __restrict__ w2,
    unsigned short* __restrict__ w1t, unsigned short* __restrict__ w2t,
    int* __restrict__ eidx, float* __restrict__ ewt)
{
  __shared__ unsigned T[8192];   // 32 KB
  const int bid = blockIdx.x;
  const int tid = threadIdx.x;

  if (bid < 2048) {
    // w1: [1024][2048] -> [2048][1024]; 8 row-tiles x 32 col-tiles (128x64)
    int e = bid >> 8, rem = bid & 255;
    int by = rem >> 5, bx = rem & 31;
    transpose_tile_glds(w1 + (size_t)e * D_MODEL * D_FF,
                        w1t + (size_t)e * D_MODEL * D_FF,
                        D_MODEL, D_FF, by * 128, bx * 64, T, tid);
    return;
  }
  if (bid < 4096) {
    // w2: [2048][1024] -> [1024][2048]; 16 x 16
    int b = bid - 2048;
    int e = b >> 8, rem = b & 255;
    int by = rem >> 4, bx = rem & 15;
    transpose_tile_glds(w2 + (size_t)e * D_MODEL * D_FF,
                        w2t + (size_t)e * D_MODEL * D_FF,
                        D_FF, D_MODEL, by * 128, bx * 64, T, tid);
    return;
  }
  // router: fp32 logits, top-2, softmax
  const int rb = bid - 4096;
  const int wv = tid >> 6, lane = tid & 63;
  const int token = rb * 4 + wv;
  const float4* xr4 = (const float4*)(x + (size_t)token * D_MODEL);
  const float4* gw4 = (const float4*)gw;

  float acc[8] = {};
  #pragma unroll
  for (int it = 0; it < 4; ++it) {
    float4 xv = xr4[it * 64 + lane];
    int d0 = it * 256 + lane * 4;
    #pragma unroll
    for (int i = 0; i < 4; ++i) {
      int d = d0 + i;
      float4 g0 = gw4[d * 2];
      float4 g1 = gw4[d * 2 + 1];
      float xs = (i == 0) ? xv.x : (i == 1) ? xv.y : (i == 2) ? xv.z : xv.w;
      acc[0] += xs * g0.x; acc[1] += xs * g0.y;
      acc[2] += xs * g0.z; acc[3] += xs * g0.w;
      acc[4] += xs * g1.x; acc[5] += xs * g1.y;
      acc[6] += xs * g1.z; acc[7] += xs * g1.w;
    }
  }
  #pragma unroll
  for (int m = 1; m < 64; m <<= 1) {
    #pragma unroll
    for (int k = 0; k < 8; ++k) acc[k] += __shfl_xor(acc[k], m);
  }
  if (lane == 0) {
    int i1 = 0; float v1 = acc[0];
    #pragma unroll
    for (int k = 1; k < 8; ++k) if (acc[k] > v1) { v1 = acc[k]; i1 = k; }
    int i2 = -1; float v2 = -1e30f;
    #pragma unroll
    for (int k = 0; k < 8; ++k) if (k != i1 && acc[k] > v2) { v2 = acc[k]; i2 = k; }
    float t  = __expf(v2 - v1);
    float wa = 1.f / (1.f + t);
    float wb = t * wa;
    eidx[token * 2 + 0] = i1; eidx[token * 2 + 1] = i2;
    ewt [token * 2 + 0] = wa; ewt [token * 2 + 1] = wb;
  }
}

// ------- Scan: 1024 threads, 8 assigns/thread; emits 256-row tiles -------
__global__ __launch_bounds__(1024) void scan_k(
    const int* __restrict__ eidx, const float* __restrict__ ewt,
    int* __restrict__ counts, int* __restrict__ offsets,
    int* __restrict__ rowtok, float* __restrict__ rowwt, int* __restrict__ rowof,
    int* __restrict__ tile_e, int* __restrict__ tile_m0, int* __restrict__ tile_n)
{
  __shared__ int wtot[16][9];
  __shared__ int woff[16][9];
  __shared__ int soff[8];
  const int t = threadIdx.x, w = t >> 6, lane = t & 63;

  int4 a = ((const int4*)eidx)[t * 2];
  int4 b = ((const int4*)eidx)[t * 2 + 1];
  int my[8] = {a.x, a.y, a.z, a.w, b.x, b.y, b.z, b.w};
  int pre[8], local[8] = {};
  #pragma unroll
  for (int i = 0; i < 8; ++i) { pre[i] = local[my[i]]; local[my[i]]++; }

  int inc[8];
  #pragma unroll
  for (int e = 0; e < 8; ++e) inc[e] = local[e];
  #pragma unroll
  for (int d = 1; d < 64; d <<= 1) {
    #pragma unroll
    for (int e = 0; e < 8; ++e) {
      int v = __shfl_up(inc[e], d);
      if (lane >= d) inc[e] += v;
    }
  }
  if (lane == 63) {
    #pragma unroll
    for (int e = 0; e < 8; ++e) wtot[w][e] = inc[e];
  }
  __syncthreads();

  if (t < 8) {
    int e = t, run = 0;
    #pragma unroll
    for (int ww = 0; ww < 16; ++ww) { woff[ww][e] = run; run += wtot[ww][e]; }
    wtot[0][e] = run;
  }
  __syncthreads();

  if (t == 0) {
    int o = 0, tt = 0;
    for (int e = 0; e < 8; ++e) {
      int c = wtot[0][e];
      counts[e] = c;
      offsets[e] = o;
      soff[e] = o;
      int nt = (c + 255) >> 8;                       // 256-row tiles
      for (int i = 0; i < nt; ++i) { tile_e[tt] = e; tile_m0[tt] = i * 256; ++tt; }
      o += c;
    }
    tile_n[0] = tt;
  }
  __syncthreads();

  int base_[8];
  #pragma unroll
  for (int e = 0; e < 8; ++e) base_[e] = soff[e] + woff[w][e] + inc[e] - local[e];

  float4 wa4 = ((const float4*)ewt)[t * 2];
  float4 wb4 = ((const float4*)ewt)[t * 2 + 1];
  float wv[8] = {wa4.x, wa4.y, wa4.z, wa4.w, wb4.x, wb4.y, wb4.z, wb4.w};

  #pragma unroll
  for (int i = 0; i < 8; ++i) {
    int bb = t * 8 + i, e = my[i];
    int row = base_[e] + pre[i];
    rowtok[row] = bb >> 1;
    rowwt[row]  = wv[i];
    rowof[bb]   = row;
  }
}

// -------- Gather: block per row, x[token] -> bf16 Xe[row]. --------
__global__ __launch_bounds__(256) void gather_k(
    const float* __restrict__ x, const int* __restrict__ rowtok,
    unsigned short* __restrict__ Xe)
{
  const int row = blockIdx.x;
  const int token = rowtok[row];
  const float4* xr = (const float4*)(x + (size_t)token * D_MODEL);
  ushort4* dst = (ushort4*)(Xe + (size_t)row * D_MODEL);
  float4 v = xr[threadIdx.x];
  ushort4 o;
  o.x = f2b(v.x); o.y = f2b(v.y); o.z = f2b(v.z); o.w = f2b(v.w);
  dst[threadIdx.x] = o;
}

// ---------------- Segmented bf16 MFMA GEMM, 256x256 tile, BK=64, 8 waves ----------------
// R12: 2-tile-deep prefetch.  All 8 stages for tile t+2 issue after the bottom
// barrier of tile t (into the buffer just vacated); vmcnt(8) at top of tile t
// retires t's loads with t+1's 8 fully in flight (~full-tile prefetch distance,
// was ~1 phase).  2 barriers/tile; compiler schedules the 24 ds_reads across all
// 32 MFMAs (fine-grained lgkmcnt).  T2 swizzle via inverse-swizzled global src.
// MODE 1: Hout = bf16(silu(A.Bt^T))   MODE 2: Hout = bf16(rowwt * A.Bt^T)
template<int K, int N, int MODE>
__global__ __launch_bounds__(512) void moe_gemm_k(
    const unsigned short* __restrict__ A,
    const unsigned short* __restrict__ Bt,
    unsigned short* __restrict__ Hout,
    const int* __restrict__ counts, const int* __restrict__ offsets,
    const float* __restrict__ rowwt,
    const int* __restrict__ tile_e, const int* __restrict__ tile_m0,
    const int* __restrict__ tile_n)
{
  constexpr int BN    = 256;
  constexpr int RT    = 512;          // staged rows per K-tile (256 A + 256 B)
  constexpr int LOADS = 8;            // global_load_lds per thread per K-tile
  constexpr int JF    = 4;            // j-fragments per wave
  constexpr int NT    = K / 64;       // K-tiles (>= 2)
  constexpr int NTN   = N / BN;       // n-tiles
  constexpr int WN    = 64;           // cols per wave

  __shared__ char lds[2 * RT * 128];  // 128 KB

  // XCD-aware swizzle: consecutive wg share the A-panel (same tile t_).
  const int nwg = gridDim.x;          // divisible by 8
  const int bid = blockIdx.x;
  const int wg  = (bid & 7) * (nwg >> 3) + (bid >> 3);
  const int t_  = wg / NTN;
  if (t_ >= tile_n[0]) return;
  const int e    = tile_e[t_];
  const int m0   = tile_m0[t_];
  const int n0   = (wg % NTN) * BN;
  const int cnt  = counts[e];
  const int base = offsets[e];

  const int tid  = threadIdx.x;
  const int l    = tid & 63;
  const int w    = tid >> 6;          // wave 0..7
  const int wm   = w >> 2;            // 0..1 : 128-row half
  const int wn   = w & 3;             // 0..3 : 64-col slice
  const int col  = l & 15, quad = l >> 4;

  const unsigned short* Aseg = A + (size_t)base * K;
  const unsigned short* Bseg = Bt + (size_t)e * ((size_t)N * K);

  const int w8 = w * 8, l3 = l >> 3;
  const int ckst = ((l & 7) ^ l3) << 3;   // inverse-swizzled k-element offset

  auto stage_one = [&](int n, int k0s, char* bw) {
    const unsigned short* src = (n < 4)
      ? Aseg + (size_t)(m0 + n * 64 + w8 + l3) * K + (k0s + ckst)
      : Bseg + (size_t)(n0 + (n - 4) * 64 + w8 + l3) * K + (k0s + ckst);
    __builtin_amdgcn_global_load_lds((gl_void*)src,
        (lds_void*)(bw + (n * 8 + w) * 1024), 16, 0, 0);
  };

  // prologue: tile 0 -> buf0, tile 1 -> buf1 (16 loads in flight)
  #pragma unroll
  for (int n = 0; n < LOADS; ++n) stage_one(n, 0, lds);
  #pragma unroll
  for (int n = 0; n < LOADS; ++n) stage_one(n, 64, lds + RT * 128);

  const int abyte = (wm * 128 + col) * 128;          // A frag base row byte
  const int bbyte = (256 + wn * WN + col) * 128;     // B frag base row byte

  f32x4 acc[8][JF] = {};

  for (int t = 0; t < NT; ++t) {
    char* bufR = lds + (t & 1) * (RT * 128);
    if (t + 1 < NT) {
      asm volatile("s_waitcnt vmcnt(8)" ::: "memory");  // tile t landed; t+1 in flight
    } else {
      asm volatile("s_waitcnt vmcnt(0)" ::: "memory");
    }
    asm volatile("s_barrier" ::: "memory");

    bf16x8 bfr[2][JF];
    #pragma unroll
    for (int ks = 0; ks < 2; ++ks) {
      const int cb = ((((ks << 2) | quad) ^ (col & 7)) << 4);
      #pragma unroll
      for (int j = 0; j < JF; ++j)
        bfr[ks][j] = *(const bf16x8*)(bufR + bbyte + j * 2048 + cb);
    }
    #pragma unroll
    for (int ks = 0; ks < 2; ++ks) {
      const int cb = ((((ks << 2) | quad) ^ (col & 7)) << 4);
      #pragma unroll
      for (int ih = 0; ih < 2; ++ih) {
        bf16x8 af[4];
        #pragma unroll
        for (int i = 0; i < 4; ++i)
          af[i] = *(const bf16x8*)(bufR + abyte + (ih * 4 + i) * 2048 + cb);
        __builtin_amdgcn_s_setprio(1);
        #pragma unroll
        for (int i = 0; i < 4; ++i)
          #pragma unroll
          for (int j = 0; j < JF; ++j)
            acc[ih * 4 + i][j] = __builtin_amdgcn_mfma_f32_16x16x32_bf16(
                af[i], bfr[ks][j], acc[ih * 4 + i][j], 0, 0, 0);
        __builtin_amdgcn_s_setprio(0);
      }
    }
    asm volatile("s_barrier" ::: "memory");   // all bufR reads done (dep-drained)
    if (t + 2 < NT) {
      #pragma unroll
      for (int n = 0; n < LOADS; ++n) stage_one(n, (t + 2) * 64, bufR);
    }
  }

  // Epilogue. C/D layout: col = lane&15, row = quad*4 + reg  [m89/m91 verified]
  #pragma unroll
  for (int i = 0; i < 8; ++i) {
    #pragma unroll
    for (int reg = 0; reg < 4; ++reg) {
      int r = m0 + wm * 128 + i * 16 + quad * 4 + reg;
      if (r < cnt) {
        unsigned short* hrow = Hout + (size_t)(base + r) * N + (n0 + wn * WN + col);
        if (MODE == 1) {
          #pragma unroll
          for (int j = 0; j < JF; ++j) {
            float v = acc[i][j][reg];
            float s = v / (1.f + __expf(-v));   // silu
            hrow[j * 16] = f2b(s);
          }
        } else {
          float wgt = rowwt[base + r];
          #pragma unroll
          for (int j = 0; j < JF; ++j)
            hrow[j * 16] = f2b(wgt * acc[i][j][reg]);
        }
      }
    }
  }
}

// ------- Combine: out[t] = Y[rowof[2t]] + Y[rowof[2t+1]] (weights pre-applied) -------
__global__ __launch_bounds__(256) void combine_k(
    const unsigned short* __restrict__ Y, const int* __restrict__ rowof,
    float* __restrict__ out)
{
  const int token = blockIdx.x;
  const int r1 = rowof[token * 2];
  const int r2 = rowof[token * 2 + 1];
  const int d4 = threadIdx.x;
  ushort4 a = *(const ushort4*)(Y + (size_t)r1 * D_MODEL + d4 * 4);
  ushort4 b = *(const ushort4*)(Y + (size_t)r2 * D_MODEL + d4 * 4);
  float4 o;
  o.x = b2f(a.x) + b2f(b.x);
  o.y = b2f(a.y) + b2f(b.y);
  o.z = b2f(a.z) + b2f(b.z);
  o.w = b2f(a.w) + b2f(b.w);
  *(float4*)(out + (size_t)token * D_MODEL + d4 * 4) = o;
}

extern "C" void kernel_launch(void* const* d_in, const int* in_sizes, int n_in,
                              void* d_out, int out_size, void* d_ws, size_t ws_size,
                              hipStream_t stream) {
  const float* x  = (const float*)d_in[0];
  const float* gw = (const float*)d_in[1];
  const float* w1 = (const float*)d_in[2];
  const float* w2 = (const float*)d_in[3];
  float* out = (float*)d_out;

  char* ws = (char*)d_ws;
  size_t off = 0;
  auto alloc = [&](size_t bytes) -> char* {
    char* p = ws + off; off += (bytes + 255) & ~(size_t)255; return p;
  };
  int*   ctrl    = (int*)alloc(1024);     // counts[8] | offsets[8] | tile_n | tiles
  int*   counts  = ctrl;
  int*   offsets = ctrl + 8;
  int*   tile_n  = ctrl + 16;
  int*   tile_e  = ctrl + 32;             // [MAXTILE]
  int*   tile_m0 = ctrl + 32 + MAXTILE;   // [MAXTILE]
  int*   eidx    = (int*)  alloc((size_t)NASSIGN * 4);
  float* ewt     = (float*)alloc((size_t)NASSIGN * 4);
  int*   rowtok  = (int*)  alloc((size_t)NASSIGN * 4);
  float* rowwt   = (float*)alloc((size_t)NASSIGN * 4);
  int*   rowof   = (int*)  alloc((size_t)NASSIGN * 4);
  unsigned short* Xe  = (unsigned short*)alloc((size_t)(NASSIGN + 256) * D_MODEL * 2);
  unsigned short* H   = (unsigned short*)alloc((size_t)(NASSIGN + 256) * D_FF * 2);
  unsigned short* Y   = (unsigned short*)alloc((size_t)(NASSIGN + 256) * D_MODEL * 2);
  unsigned short* w1t = (unsigned short*)alloc((size_t)N_EXP * D_MODEL * D_FF * 2);
  unsigned short* w2t = (unsigned short*)alloc((size_t)N_EXP * D_MODEL * D_FF * 2);

  prep_k<<<4096 + NTOK / 4, 256, 0, stream>>>(x, gw, w1, w2, w1t, w2t, eidx, ewt);
  scan_k<<<1, 1024, 0, stream>>>(eidx, ewt, counts, offsets, rowtok, rowwt, rowof,
                                 tile_e, tile_m0, tile_n);
  gather_k<<<NASSIGN, 256, 0, stream>>>(x, rowtok, Xe);

  // GEMM1: 40 M-tiles x 8 n-tiles = 320 blocks; GEMM2: 40 x 4 = 160 (single round)
  moe_gemm_k<D_MODEL, D_FF, 1><<<320, 512, 0, stream>>>(
      Xe, w1t, H, counts, offsets, rowwt, tile_e, tile_m0, tile_n);
  moe_gemm_k<D_FF, D_MODEL, 2><<<160, 512, 0, stream>>>(
      H, w2t, Y, counts, offsets, rowwt, tile_e, tile_m0, tile_n);
  combine_k<<<NTOK, 256, 0, stream>>>(Y, rowof, out);
}

// Round 17
// 357.325 us; speedup vs baseline: 1.0640x; 1.0640x over previous
//
#include <hip/hip_runtime.h>
#include <cstdint>
#include <cstddef>

#define D_MODEL 1024
#define D_FF    2048
#define N_EXP   8
#define NTOK    4096          // B*S
#define NASSIGN (NTOK * 2)    // top-2
#define MAXTILE 72            // ctrl-buffer layout (256-row tiles use <= 40)

typedef __bf16 bf16_t;
typedef bf16_t bf16x8 __attribute__((ext_vector_type(8)));
typedef float  f32x4  __attribute__((ext_vector_type(4)));

typedef __attribute__((address_space(3))) void       lds_void;
typedef const __attribute__((address_space(1))) void gl_void;

__device__ __forceinline__ unsigned short f2b(float f) {
  union { float f; unsigned u; } v; v.f = f;
  unsigned u = v.u;
  unsigned r = (u + 0x7FFFu + ((u >> 16) & 1u)) >> 16;  // RNE
  return (unsigned short)r;
}
__device__ __forceinline__ float b2f(unsigned short b) {
  union { unsigned u; float f; } v; v.u = ((unsigned)b) << 16; return v.f;
}

// ---------------- Prep: w1/w2 transpose (128x64 tiles, R10 version) | router --------
// R17: REVERT to R10's measured-80us transpose.  R16's glds+permuted-source variant
// amplified traffic (FETCH +44%, WRITE 2x, 3.1M bank conflicts) and regressed to
// 105us — pre-swizzling glds sources below the 64B sector granule defeats
// coalescing.  This version: coalesced 256B reads AND writes, LDS u32 [128][33]
// with col XOR ((row>>5)<<3), 0 measured conflicts.
__device__ __forceinline__ void transpose_tile_128x64(
    const float* __restrict__ ein, unsigned short* __restrict__ eout,
    int R /*input rows = out stride*/, int C /*input cols*/,
    int r0, int c0, unsigned* T, int tid)
{
  const int g = tid >> 4;        // 0..15
  const int m = tid & 15;        // 0..15

  float4 v[8];
  #pragma unroll
  for (int i = 0; i < 8; ++i)
    v[i] = *(const float4*)(ein + (size_t)(r0 + i * 16 + g) * C + c0 + m * 4);

  #pragma unroll
  for (int i = 0; i < 8; ++i) {
    int r  = i * 16 + g;
    int cx = (r >> 5) << 3;
    unsigned lo = (unsigned)f2b(v[i].x) | ((unsigned)f2b(v[i].y) << 16);
    unsigned hi = (unsigned)f2b(v[i].z) | ((unsigned)f2b(v[i].w) << 16);
    T[r * 33 + ((2 * m)     ^ cx)] = lo;   // u32 col j = input cols c0+2j, c0+2j+1
    T[r * 33 + ((2 * m + 1) ^ cx)] = hi;
  }
  __syncthreads();

  const int c    = tid >> 2;       // 0..63 : output row (input col)
  const int s4   = tid & 3;        // 64B segment along r
  const int half = (c & 1) * 16;
  const int ccol = (c >> 1) ^ (s4 << 3);   // r in [32*s4, 32*s4+31] -> cx = s4<<3
  unsigned ow[16];
  #pragma unroll
  for (int j2 = 0; j2 < 16; ++j2) {
    int r = s4 * 32 + 2 * j2;
    unsigned lo16 = (T[r * 33 + ccol] >> half) & 0xFFFFu;
    unsigned hi16 = (T[(r + 1) * 33 + ccol] >> half) & 0xFFFFu;
    ow[j2] = lo16 | (hi16 << 16);
  }
  uint4* dst = (uint4*)(eout + (size_t)(c0 + c) * R + r0 + s4 * 32);
  dst[0] = *(uint4*)&ow[0];
  dst[1] = *(uint4*)&ow[4];
  dst[2] = *(uint4*)&ow[8];
  dst[3] = *(uint4*)&ow[12];
}

__global__ __launch_bounds__(256) void prep_k(
    const float* __restrict__ x, const float* __restrict__ gw,
    const float* __restrict__ w1, const float* __restrict__ w2,
    unsigned short* __restrict__ w1t, unsigned short* __restrict__ w2t,
    int* __restrict__ eidx, float* __restrict__ ewt)
{
  __shared__ unsigned T[128 * 33];
  const int bid = blockIdx.x;
  const int tid = threadIdx.x;

  if (bid < 2048) {
    // w1: [1024][2048] -> [2048][1024]; 8 row-tiles x 32 col-tiles
    int e = bid >> 8, rem = bid & 255;
    int by = rem >> 5, bx = rem & 31;
    transpose_tile_128x64(w1 + (size_t)e * D_MODEL * D_FF,
                          w1t + (size_t)e * D_MODEL * D_FF,
                          D_MODEL, D_FF, by * 128, bx * 64, T, tid);
    return;
  }
  if (bid < 4096) {
    // w2: [2048][1024] -> [1024][2048]; 16 x 16
    int b = bid - 2048;
    int e = b >> 8, rem = b & 255;
    int by = rem >> 4, bx = rem & 15;
    transpose_tile_128x64(w2 + (size_t)e * D_MODEL * D_FF,
                          w2t + (size_t)e * D_MODEL * D_FF,
                          D_FF, D_MODEL, by * 128, bx * 64, T, tid);
    return;
  }
  // router: fp32 logits, top-2, softmax
  const int rb = bid - 4096;
  const int wv = tid >> 6, lane = tid & 63;
  const int token = rb * 4 + wv;
  const float4* xr4 = (const float4*)(x + (size_t)token * D_MODEL);
  const float4* gw4 = (const float4*)gw;

  float acc[8] = {};
  #pragma unroll
  for (int it = 0; it < 4; ++it) {
    float4 xv = xr4[it * 64 + lane];
    int d0 = it * 256 + lane * 4;
    #pragma unroll
    for (int i = 0; i < 4; ++i) {
      int d = d0 + i;
      float4 g0 = gw4[d * 2];
      float4 g1 = gw4[d * 2 + 1];
      float xs = (i == 0) ? xv.x : (i == 1) ? xv.y : (i == 2) ? xv.z : xv.w;
      acc[0] += xs * g0.x; acc[1] += xs * g0.y;
      acc[2] += xs * g0.z; acc[3] += xs * g0.w;
      acc[4] += xs * g1.x; acc[5] += xs * g1.y;
      acc[6] += xs * g1.z; acc[7] += xs * g1.w;
    }
  }
  #pragma unroll
  for (int m = 1; m < 64; m <<= 1) {
    #pragma unroll
    for (int k = 0; k < 8; ++k) acc[k] += __shfl_xor(acc[k], m);
  }
  if (lane == 0) {
    int i1 = 0; float v1 = acc[0];
    #pragma unroll
    for (int k = 1; k < 8; ++k) if (acc[k] > v1) { v1 = acc[k]; i1 = k; }
    int i2 = -1; float v2 = -1e30f;
    #pragma unroll
    for (int k = 0; k < 8; ++k) if (k != i1 && acc[k] > v2) { v2 = acc[k]; i2 = k; }
    float t  = __expf(v2 - v1);
    float wa = 1.f / (1.f + t);
    float wb = t * wa;
    eidx[token * 2 + 0] = i1; eidx[token * 2 + 1] = i2;
    ewt [token * 2 + 0] = wa; ewt [token * 2 + 1] = wb;
  }
}

// ------- Scan: 1024 threads, 8 assigns/thread; emits 256-row tiles -------
__global__ __launch_bounds__(1024) void scan_k(
    const int* __restrict__ eidx, const float* __restrict__ ewt,
    int* __restrict__ counts, int* __restrict__ offsets,
    int* __restrict__ rowtok, float* __restrict__ rowwt, int* __restrict__ rowof,
    int* __restrict__ tile_e, int* __restrict__ tile_m0, int* __restrict__ tile_n)
{
  __shared__ int wtot[16][9];
  __shared__ int woff[16][9];
  __shared__ int soff[8];
  const int t = threadIdx.x, w = t >> 6, lane = t & 63;

  int4 a = ((const int4*)eidx)[t * 2];
  int4 b = ((const int4*)eidx)[t * 2 + 1];
  int my[8] = {a.x, a.y, a.z, a.w, b.x, b.y, b.z, b.w};
  int pre[8], local[8] = {};
  #pragma unroll
  for (int i = 0; i < 8; ++i) { pre[i] = local[my[i]]; local[my[i]]++; }

  int inc[8];
  #pragma unroll
  for (int e = 0; e < 8; ++e) inc[e] = local[e];
  #pragma unroll
  for (int d = 1; d < 64; d <<= 1) {
    #pragma unroll
    for (int e = 0; e < 8; ++e) {
      int v = __shfl_up(inc[e], d);
      if (lane >= d) inc[e] += v;
    }
  }
  if (lane == 63) {
    #pragma unroll
    for (int e = 0; e < 8; ++e) wtot[w][e] = inc[e];
  }
  __syncthreads();

  if (t < 8) {
    int e = t, run = 0;
    #pragma unroll
    for (int ww = 0; ww < 16; ++ww) { woff[ww][e] = run; run += wtot[ww][e]; }
    wtot[0][e] = run;
  }
  __syncthreads();

  if (t == 0) {
    int o = 0, tt = 0;
    for (int e = 0; e < 8; ++e) {
      int c = wtot[0][e];
      counts[e] = c;
      offsets[e] = o;
      soff[e] = o;
      int nt = (c + 255) >> 8;                       // 256-row tiles
      for (int i = 0; i < nt; ++i) { tile_e[tt] = e; tile_m0[tt] = i * 256; ++tt; }
      o += c;
    }
    tile_n[0] = tt;
  }
  __syncthreads();

  int base_[8];
  #pragma unroll
  for (int e = 0; e < 8; ++e) base_[e] = soff[e] + woff[w][e] + inc[e] - local[e];

  float4 wa4 = ((const float4*)ewt)[t * 2];
  float4 wb4 = ((const float4*)ewt)[t * 2 + 1];
  float wv[8] = {wa4.x, wa4.y, wa4.z, wa4.w, wb4.x, wb4.y, wb4.z, wb4.w};

  #pragma unroll
  for (int i = 0; i < 8; ++i) {
    int bb = t * 8 + i, e = my[i];
    int row = base_[e] + pre[i];
    rowtok[row] = bb >> 1;
    rowwt[row]  = wv[i];
    rowof[bb]   = row;
  }
}

// -------- Gather: block per row, x[token] -> bf16 Xe[row]. --------
__global__ __launch_bounds__(256) void gather_k(
    const float* __restrict__ x, const int* __restrict__ rowtok,
    unsigned short* __restrict__ Xe)
{
  const int row = blockIdx.x;
  const int token = rowtok[row];
  const float4* xr = (const float4*)(x + (size_t)token * D_MODEL);
  ushort4* dst = (ushort4*)(Xe + (size_t)row * D_MODEL);
  float4 v = xr[threadIdx.x];
  ushort4 o;
  o.x = f2b(v.x); o.y = f2b(v.y); o.z = f2b(v.z); o.w = f2b(v.w);
  dst[threadIdx.x] = o;
}

// ---------------- Segmented bf16 MFMA GEMM, 256x256 tile, BK=64, 8 waves ----------------
// R12: 2-tile-deep prefetch.  All 8 stages for tile t+2 issue after the bottom
// barrier of tile t (into the buffer just vacated); vmcnt(8) at top of tile t
// retires t's loads with t+1's 8 fully in flight.  2 barriers/tile; compiler
// schedules the 24 ds_reads across all 32 MFMAs (fine-grained lgkmcnt).
// T2 swizzle via inverse-swizzled global src (within-128B-line permutation only).
// MODE 1: Hout = bf16(silu(A.Bt^T))   MODE 2: Hout = bf16(rowwt * A.Bt^T)
template<int K, int N, int MODE>
__global__ __launch_bounds__(512) void moe_gemm_k(
    const unsigned short* __restrict__ A,
    const unsigned short* __restrict__ Bt,
    unsigned short* __restrict__ Hout,
    const int* __restrict__ counts, const int* __restrict__ offsets,
    const float* __restrict__ rowwt,
    const int* __restrict__ tile_e, const int* __restrict__ tile_m0,
    const int* __restrict__ tile_n)
{
  constexpr int BN    = 256;
  constexpr int RT    = 512;          // staged rows per K-tile (256 A + 256 B)
  constexpr int LOADS = 8;            // global_load_lds per thread per K-tile
  constexpr int JF    = 4;            // j-fragments per wave
  constexpr int NT    = K / 64;       // K-tiles (>= 2)
  constexpr int NTN   = N / BN;       // n-tiles
  constexpr int WN    = 64;           // cols per wave

  __shared__ char lds[2 * RT * 128];  // 128 KB

  // XCD-aware swizzle: consecutive wg share the A-panel (same tile t_).
  const int nwg = gridDim.x;          // divisible by 8
  const int bid = blockIdx.x;
  const int wg  = (bid & 7) * (nwg >> 3) + (bid >> 3);
  const int t_  = wg / NTN;
  if (t_ >= tile_n[0]) return;
  const int e    = tile_e[t_];
  const int m0   = tile_m0[t_];
  const int n0   = (wg % NTN) * BN;
  const int cnt  = counts[e];
  const int base = offsets[e];

  const int tid  = threadIdx.x;
  const int l    = tid & 63;
  const int w    = tid >> 6;          // wave 0..7
  const int wm   = w >> 2;            // 0..1 : 128-row half
  const int wn   = w & 3;             // 0..3 : 64-col slice
  const int col  = l & 15, quad = l >> 4;

  const unsigned short* Aseg = A + (size_t)base * K;
  const unsigned short* Bseg = Bt + (size_t)e * ((size_t)N * K);

  const int w8 = w * 8, l3 = l >> 3;
  const int ckst = ((l & 7) ^ l3) << 3;   // inverse-swizzled k-element offset

  auto stage_one = [&](int n, int k0s, char* bw) {
    const unsigned short* src = (n < 4)
      ? Aseg + (size_t)(m0 + n * 64 + w8 + l3) * K + (k0s + ckst)
      : Bseg + (size_t)(n0 + (n - 4) * 64 + w8 + l3) * K + (k0s + ckst);
    __builtin_amdgcn_global_load_lds((gl_void*)src,
        (lds_void*)(bw + (n * 8 + w) * 1024), 16, 0, 0);
  };

  // prologue: tile 0 -> buf0, tile 1 -> buf1 (16 loads in flight)
  #pragma unroll
  for (int n = 0; n < LOADS; ++n) stage_one(n, 0, lds);
  #pragma unroll
  for (int n = 0; n < LOADS; ++n) stage_one(n, 64, lds + RT * 128);

  const int abyte = (wm * 128 + col) * 128;          // A frag base row byte
  const int bbyte = (256 + wn * WN + col) * 128;     // B frag base row byte

  f32x4 acc[8][JF] = {};

  for (int t = 0; t < NT; ++t) {
    char* bufR = lds + (t & 1) * (RT * 128);
    if (t + 1 < NT) {
      asm volatile("s_waitcnt vmcnt(8)" ::: "memory");  // tile t landed; t+1 in flight
    } else {
      asm volatile("s_waitcnt vmcnt(0)" ::: "memory");
    }
    asm volatile("s_barrier" ::: "memory");

    bf16x8 bfr[2][JF];
    #pragma unroll
    for (int ks = 0; ks < 2; ++ks) {
      const int cb = ((((ks << 2) | quad) ^ (col & 7)) << 4);
      #pragma unroll
      for (int j = 0; j < JF; ++j)
        bfr[ks][j] = *(const bf16x8*)(bufR + bbyte + j * 2048 + cb);
    }
    #pragma unroll
    for (int ks = 0; ks < 2; ++ks) {
      const int cb = ((((ks << 2) | quad) ^ (col & 7)) << 4);
      #pragma unroll
      for (int ih = 0; ih < 2; ++ih) {
        bf16x8 af[4];
        #pragma unroll
        for (int i = 0; i < 4; ++i)
          af[i] = *(const bf16x8*)(bufR + abyte + (ih * 4 + i) * 2048 + cb);
        __builtin_amdgcn_s_setprio(1);
        #pragma unroll
        for (int i = 0; i < 4; ++i)
          #pragma unroll
          for (int j = 0; j < JF; ++j)
            acc[ih * 4 + i][j] = __builtin_amdgcn_mfma_f32_16x16x32_bf16(
                af[i], bfr[ks][j], acc[ih * 4 + i][j], 0, 0, 0);
        __builtin_amdgcn_s_setprio(0);
      }
    }
    asm volatile("s_barrier" ::: "memory");   // all bufR reads done (dep-drained)
    if (t + 2 < NT) {
      #pragma unroll
      for (int n = 0; n < LOADS; ++n) stage_one(n, (t + 2) * 64, bufR);
    }
  }

  // Epilogue. C/D layout: col = lane&15, row = quad*4 + reg  [m89/m91 verified]
  #pragma unroll
  for (int i = 0; i < 8; ++i) {
    #pragma unroll
    for (int reg = 0; reg < 4; ++reg) {
      int r = m0 + wm * 128 + i * 16 + quad * 4 + reg;
      if (r < cnt) {
        unsigned short* hrow = Hout + (size_t)(base + r) * N + (n0 + wn * WN + col);
        if (MODE == 1) {
          #pragma unroll
          for (int j = 0; j < JF; ++j) {
            float v = acc[i][j][reg];
            float s = v / (1.f + __expf(-v));   // silu
            hrow[j * 16] = f2b(s);
          }
        } else {
          float wgt = rowwt[base + r];
          #pragma unroll
          for (int j = 0; j < JF; ++j)
            hrow[j * 16] = f2b(wgt * acc[i][j][reg]);
        }
      }
    }
  }
}

// ------- Combine: out[t] = Y[rowof[2t]] + Y[rowof[2t+1]] (weights pre-applied) -------
__global__ __launch_bounds__(256) void combine_k(
    const unsigned short* __restrict__ Y, const int* __restrict__ rowof,
    float* __restrict__ out)
{
  const int token = blockIdx.x;
  const int r1 = rowof[token * 2];
  const int r2 = rowof[token * 2 + 1];
  const int d4 = threadIdx.x;
  ushort4 a = *(const ushort4*)(Y + (size_t)r1 * D_MODEL + d4 * 4);
  ushort4 b = *(const ushort4*)(Y + (size_t)r2 * D_MODEL + d4 * 4);
  float4 o;
  o.x = b2f(a.x) + b2f(b.x);
  o.y = b2f(a.y) + b2f(b.y);
  o.z = b2f(a.z) + b2f(b.z);
  o.w = b2f(a.w) + b2f(b.w);
  *(float4*)(out + (size_t)token * D_MODEL + d4 * 4) = o;
}

extern "C" void kernel_launch(void* const* d_in, const int* in_sizes, int n_in,
                              void* d_out, int out_size, void* d_ws, size_t ws_size,
                              hipStream_t stream) {
  const float* x  = (const float*)d_in[0];
  const float* gw = (const float*)d_in[1];
  const float* w1 = (const float*)d_in[2];
  const float* w2 = (const float*)d_in[3];
  float* out = (float*)d_out;

  char* ws = (char*)d_ws;
  size_t off = 0;
  auto alloc = [&](size_t bytes) -> char* {
    char* p = ws + off; off += (bytes + 255) & ~(size_t)255; return p;
  };
  int*   ctrl    = (int*)alloc(1024);     // counts[8] | offsets[8] | tile_n | tiles
  int*   counts  = ctrl;
  int*   offsets = ctrl + 8;
  int*   tile_n  = ctrl + 16;
  int*   tile_e  = ctrl + 32;             // [MAXTILE]
  int*   tile_m0 = ctrl + 32 + MAXTILE;   // [MAXTILE]
  int*   eidx    = (int*)  alloc((size_t)NASSIGN * 4);
  float* ewt     = (float*)alloc((size_t)NASSIGN * 4);
  int*   rowtok  = (int*)  alloc((size_t)NASSIGN * 4);
  float* rowwt   = (float*)alloc((size_t)NASSIGN * 4);
  int*   rowof   = (int*)  alloc((size_t)NASSIGN * 4);
  unsigned short* Xe  = (unsigned short*)alloc((size_t)(NASSIGN + 256) * D_MODEL * 2);
  unsigned short* H   = (unsigned short*)alloc((size_t)(NASSIGN + 256) * D_FF * 2);
  unsigned short* Y   = (unsigned short*)alloc((size_t)(NASSIGN + 256) * D_MODEL * 2);
  unsigned short* w1t = (unsigned short*)alloc((size_t)N_EXP * D_MODEL * D_FF * 2);
  unsigned short* w2t = (unsigned short*)alloc((size_t)N_EXP * D_MODEL * D_FF * 2);

  prep_k<<<4096 + NTOK / 4, 256, 0, stream>>>(x, gw, w1, w2, w1t, w2t, eidx, ewt);
  scan_k<<<1, 1024, 0, stream>>>(eidx, ewt, counts, offsets, rowtok, rowwt, rowof,
                                 tile_e, tile_m0, tile_n);
  gather_k<<<NASSIGN, 256, 0, stream>>>(x, rowtok, Xe);

  // GEMM1: 40 M-tiles x 8 n-tiles = 320 blocks; GEMM2: 40 x 4 = 160 (single round)
  moe_gemm_k<D_MODEL, D_FF, 1><<<320, 512, 0, stream>>>(
      Xe, w1t, H, counts, offsets, rowwt, tile_e, tile_m0, tile_n);
  moe_gemm_k<D_FF, D_MODEL, 2><<<160, 512, 0, stream>>>(
      H, w2t, Y, counts, offsets, rowwt, tile_e, tile_m0, tile_n);
  combine_k<<<NTOK, 256, 0, stream>>>(Y, rowof, out);
}

// Round 19
// 333.216 us; speedup vs baseline: 1.1410x; 1.0724x over previous
//
#include <hip/hip_runtime.h>
#include <cstdint>
#include <cstddef>

#define D_MODEL 1024
#define D_FF    2048
#define N_EXP   8
#define NTOK    4096          // B*S
#define NASSIGN (NTOK * 2)    // top-2
#define MAXTILE 72            // ctrl-buffer layout (256-row tiles use <= 40)

typedef __bf16 bf16_t;
typedef bf16_t bf16x8 __attribute__((ext_vector_type(8)));
typedef float  f32x4  __attribute__((ext_vector_type(4)));

typedef __attribute__((address_space(3))) void       lds_void;
typedef const __attribute__((address_space(1))) void gl_void;

__device__ __forceinline__ unsigned short f2b(float f) {
  union { float f; unsigned u; } v; v.f = f;
  unsigned u = v.u;
  unsigned r = (u + 0x7FFFu + ((u >> 16) & 1u)) >> 16;  // RNE
  return (unsigned short)r;
}
__device__ __forceinline__ float b2f(unsigned short b) {
  union { unsigned u; float f; } v; v.u = ((unsigned)b) << 16; return v.f;
}

// ---------------- Prep: w1/w2 transpose (128x64, glds LINEAR source) | router --------
// R18: R16 showed glds raises in-flight bytes/BW (+30%) but its PERMUTED source
// amplified traffic (FETCH +44%, WRITE 2x).  This version keeps glds (fire-and-
// forget, can't be sunk: 8x16B/thread in flight) with a LINEAR source: each load
// covers 4 full 256B rows -> perfectly coalesced, no amplification.  LDS = linear
// [128][64] f32; column read-back is ~4-way conflicted (1.58x on a ~6us total LDS
// read — cheap).  RNE pack + 256B-coalesced stores identical to R10.
__device__ __forceinline__ void transpose_tile_glin(
    const float* __restrict__ ein, unsigned short* __restrict__ eout,
    int R /*out stride*/, int C /*in cols*/, int r0, int c0,
    unsigned* T /*32KB*/, int tid)
{
  const int l = tid & 63;
  const int w = tid >> 6;        // wave 0..3

  #pragma unroll
  for (int n = 0; n < 8; ++n) {
    int g   = n * 4 + w;                       // group 0..31 = rows 4g..4g+3
    int row = g * 4 + (l >> 4);
    const float* src = ein + (size_t)(r0 + row) * C + c0 + ((l & 15) << 2);
    __builtin_amdgcn_global_load_lds((gl_void*)src,
        (lds_void*)((char*)T + g * 1024), 16, 0, 0);
  }
  __syncthreads();   // drains vmcnt, publishes LDS

  const int c  = tid >> 2;       // 0..63 : output row (input col)
  const int s4 = tid & 3;        // 32-row segment along r
  unsigned ow[16];
  #pragma unroll
  for (int j2 = 0; j2 < 16; ++j2) {
    int r = s4 * 32 + 2 * j2;
    float lo, hi;
    { union { unsigned u; float f; } v; v.u = T[r * 64 + c];       lo = v.f; }
    { union { unsigned u; float f; } v; v.u = T[(r + 1) * 64 + c]; hi = v.f; }
    ow[j2] = (unsigned)f2b(lo) | ((unsigned)f2b(hi) << 16);
  }
  uint4* dst = (uint4*)(eout + (size_t)(c0 + c) * R + r0 + s4 * 32);
  dst[0] = *(uint4*)&ow[0];
  dst[1] = *(uint4*)&ow[4];
  dst[2] = *(uint4*)&ow[8];
  dst[3] = *(uint4*)&ow[12];
}

__global__ __launch_bounds__(256) void prep_k(
    const float* __restrict__ x, const float* __restrict__ gw,
    const float* __restrict__ w1, const float* __restrict__ w2,
    unsigned short* __restrict__ w1t, unsigned short* __restrict__ w2t,
    int* __restrict__ eidx, float* __restrict__ ewt)
{
  __shared__ unsigned T[8192];   // 32 KB
  const int bid = blockIdx.x;
  const int tid = threadIdx.x;

  if (bid < 2048) {
    // w1: [1024][2048] -> [2048][1024]; 8 row-tiles x 32 col-tiles (128x64)
    int e = bid >> 8, rem = bid & 255;
    int by = rem >> 5, bx = rem & 31;
    transpose_tile_glin(w1 + (size_t)e * D_MODEL * D_FF,
                        w1t + (size_t)e * D_MODEL * D_FF,
                        D_MODEL, D_FF, by * 128, bx * 64, T, tid);
    return;
  }
  if (bid < 4096) {
    // w2: [2048][1024] -> [1024][2048]; 16 x 16
    int b = bid - 2048;
    int e = b >> 8, rem = b & 255;
    int by = rem >> 4, bx = rem & 15;
    transpose_tile_glin(w2 + (size_t)e * D_MODEL * D_FF,
                        w2t + (size_t)e * D_MODEL * D_FF,
                        D_FF, D_MODEL, by * 128, bx * 64, T, tid);
    return;
  }
  // router: fp32 logits, top-2, softmax
  const int rb = bid - 4096;
  const int wv = tid >> 6, lane = tid & 63;
  const int token = rb * 4 + wv;
  const float4* xr4 = (const float4*)(x + (size_t)token * D_MODEL);
  const float4* gw4 = (const float4*)gw;

  float acc[8] = {};
  #pragma unroll
  for (int it = 0; it < 4; ++it) {
    float4 xv = xr4[it * 64 + lane];
    int d0 = it * 256 + lane * 4;
    #pragma unroll
    for (int i = 0; i < 4; ++i) {
      int d = d0 + i;
      float4 g0 = gw4[d * 2];
      float4 g1 = gw4[d * 2 + 1];
      float xs = (i == 0) ? xv.x : (i == 1) ? xv.y : (i == 2) ? xv.z : xv.w;
      acc[0] += xs * g0.x; acc[1] += xs * g0.y;
      acc[2] += xs * g0.z; acc[3] += xs * g0.w;
      acc[4] += xs * g1.x; acc[5] += xs * g1.y;
      acc[6] += xs * g1.z; acc[7] += xs * g1.w;
    }
  }
  #pragma unroll
  for (int m = 1; m < 64; m <<= 1) {
    #pragma unroll
    for (int k = 0; k < 8; ++k) acc[k] += __shfl_xor(acc[k], m);
  }
  if (lane == 0) {
    int i1 = 0; float v1 = acc[0];
    #pragma unroll
    for (int k = 1; k < 8; ++k) if (acc[k] > v1) { v1 = acc[k]; i1 = k; }
    int i2 = -1; float v2 = -1e30f;
    #pragma unroll
    for (int k = 0; k < 8; ++k) if (k != i1 && acc[k] > v2) { v2 = acc[k]; i2 = k; }
    float t  = __expf(v2 - v1);
    float wa = 1.f / (1.f + t);
    float wb = t * wa;
    eidx[token * 2 + 0] = i1; eidx[token * 2 + 1] = i2;
    ewt [token * 2 + 0] = wa; ewt [token * 2 + 1] = wb;
  }
}

// ------- Scan: 1024 threads, 8 assigns/thread; emits 256-row tiles -------
__global__ __launch_bounds__(1024) void scan_k(
    const int* __restrict__ eidx, const float* __restrict__ ewt,
    int* __restrict__ counts, int* __restrict__ offsets,
    int* __restrict__ rowtok, float* __restrict__ rowwt, int* __restrict__ rowof,
    int* __restrict__ tile_e, int* __restrict__ tile_m0, int* __restrict__ tile_n)
{
  __shared__ int wtot[16][9];
  __shared__ int woff[16][9];
  __shared__ int soff[8];
  const int t = threadIdx.x, w = t >> 6, lane = t & 63;

  int4 a = ((const int4*)eidx)[t * 2];
  int4 b = ((const int4*)eidx)[t * 2 + 1];
  int my[8] = {a.x, a.y, a.z, a.w, b.x, b.y, b.z, b.w};
  int pre[8], local[8] = {};
  #pragma unroll
  for (int i = 0; i < 8; ++i) { pre[i] = local[my[i]]; local[my[i]]++; }

  int inc[8];
  #pragma unroll
  for (int e = 0; e < 8; ++e) inc[e] = local[e];
  #pragma unroll
  for (int d = 1; d < 64; d <<= 1) {
    #pragma unroll
    for (int e = 0; e < 8; ++e) {
      int v = __shfl_up(inc[e], d);
      if (lane >= d) inc[e] += v;
    }
  }
  if (lane == 63) {
    #pragma unroll
    for (int e = 0; e < 8; ++e) wtot[w][e] = inc[e];
  }
  __syncthreads();

  if (t < 8) {
    int e = t, run = 0;
    #pragma unroll
    for (int ww = 0; ww < 16; ++ww) { woff[ww][e] = run; run += wtot[ww][e]; }
    wtot[0][e] = run;
  }
  __syncthreads();

  if (t == 0) {
    int o = 0, tt = 0;
    for (int e = 0; e < 8; ++e) {
      int c = wtot[0][e];
      counts[e] = c;
      offsets[e] = o;
      soff[e] = o;
      int nt = (c + 255) >> 8;                       // 256-row tiles
      for (int i = 0; i < nt; ++i) { tile_e[tt] = e; tile_m0[tt] = i * 256; ++tt; }
      o += c;
    }
    tile_n[0] = tt;
  }
  __syncthreads();

  int base_[8];
  #pragma unroll
  for (int e = 0; e < 8; ++e) base_[e] = soff[e] + woff[w][e] + inc[e] - local[e];

  float4 wa4 = ((const float4*)ewt)[t * 2];
  float4 wb4 = ((const float4*)ewt)[t * 2 + 1];
  float wv[8] = {wa4.x, wa4.y, wa4.z, wa4.w, wb4.x, wb4.y, wb4.z, wb4.w};

  #pragma unroll
  for (int i = 0; i < 8; ++i) {
    int bb = t * 8 + i, e = my[i];
    int row = base_[e] + pre[i];
    rowtok[row] = bb >> 1;
    rowwt[row]  = wv[i];
    rowof[bb]   = row;
  }
}

// -------- Gather: block per row, x[token] -> bf16 Xe[row]. --------
__global__ __launch_bounds__(256) void gather_k(
    const float* __restrict__ x, const int* __restrict__ rowtok,
    unsigned short* __restrict__ Xe)
{
  const int row = blockIdx.x;
  const int token = rowtok[row];
  const float4* xr = (const float4*)(x + (size_t)token * D_MODEL);
  ushort4* dst = (ushort4*)(Xe + (size_t)row * D_MODEL);
  float4 v = xr[threadIdx.x];
  ushort4 o;
  o.x = f2b(v.x); o.y = f2b(v.y); o.z = f2b(v.z); o.w = f2b(v.w);
  dst[threadIdx.x] = o;
}

// ---------------- Segmented bf16 MFMA GEMM, 256x256 tile, BK=64, 8 waves ----------------
// R18: REVERT to the per-phase 4-phase schedule (R11 config, part of the 335us
// best).  R17 isolated the 2-deep/2-barrier variant at +22us — per-phase pacing of
// ds_reads and stage-issues between MFMA clusters is the lever (m196), not
// prefetch depth.  Counted vmcnt(2) once per K-tile; T2 swizzle via
// inverse-swizzled global src (within-128B-line permutation only).
// MODE 1: Hout = bf16(silu(A.Bt^T))   MODE 2: Hout = bf16(rowwt * A.Bt^T)
template<int K, int N, int MODE>
__global__ __launch_bounds__(512) void moe_gemm_k(
    const unsigned short* __restrict__ A,
    const unsigned short* __restrict__ Bt,
    unsigned short* __restrict__ Hout,
    const int* __restrict__ counts, const int* __restrict__ offsets,
    const float* __restrict__ rowwt,
    const int* __restrict__ tile_e, const int* __restrict__ tile_m0,
    const int* __restrict__ tile_n)
{
  constexpr int BN    = 256;
  constexpr int RT    = 512;          // staged rows per K-tile (256 A + 256 B)
  constexpr int LOADS = 8;            // global_load_lds per thread per K-tile
  constexpr int JF    = 4;            // j-fragments per wave
  constexpr int NT    = K / 64;       // K-tiles
  constexpr int NTN   = N / BN;       // n-tiles
  constexpr int WN    = 64;           // cols per wave

  __shared__ char lds[2 * RT * 128];  // 128 KB

  // XCD-aware swizzle: consecutive wg share the A-panel (same tile t_).
  const int nwg = gridDim.x;          // divisible by 8
  const int bid = blockIdx.x;
  const int wg  = (bid & 7) * (nwg >> 3) + (bid >> 3);
  const int t_  = wg / NTN;
  if (t_ >= tile_n[0]) return;
  const int e    = tile_e[t_];
  const int m0   = tile_m0[t_];
  const int n0   = (wg % NTN) * BN;
  const int cnt  = counts[e];
  const int base = offsets[e];

  const int tid  = threadIdx.x;
  const int l    = tid & 63;
  const int w    = tid >> 6;          // wave 0..7
  const int wm   = w >> 2;            // 0..1 : 128-row half
  const int wn   = w & 3;             // 0..3 : 64-col slice
  const int col  = l & 15, quad = l >> 4;

  const unsigned short* Aseg = A + (size_t)base * K;
  const unsigned short* Bseg = Bt + (size_t)e * ((size_t)N * K);

  const int w8 = w * 8, l3 = l >> 3;
  const int ckst = ((l & 7) ^ l3) << 3;   // inverse-swizzled k-element offset

  auto stage_one = [&](int n, int k0s, char* bw) {
    const unsigned short* src = (n < 4)
      ? Aseg + (size_t)(m0 + n * 64 + w8 + l3) * K + (k0s + ckst)
      : Bseg + (size_t)(n0 + (n - 4) * 64 + w8 + l3) * K + (k0s + ckst);
    __builtin_amdgcn_global_load_lds((gl_void*)src,
        (lds_void*)(bw + (n * 8 + w) * 1024), 16, 0, 0);
  };

  // prologue: stage K-tile 0 into buffer 0
  #pragma unroll
  for (int n = 0; n < LOADS; ++n) stage_one(n, 0, lds);

  const int abyte = (wm * 128 + col) * 128;          // A frag base row byte
  const int bbyte = (256 + wn * WN + col) * 128;     // B frag base row byte

  f32x4 acc[8][JF] = {};

  for (int t = 0; t < NT; ++t) {
    char* bufR = lds + (t & 1) * (RT * 128);
    char* bufW = lds + ((t + 1) & 1) * (RT * 128);
    const int k0n = (t + 1) * 64;
    const bool hn = (t + 1 < NT);
    if (hn) {
      stage_one(0, k0n, bufW);
      stage_one(1, k0n, bufW);
      asm volatile("s_waitcnt vmcnt(2)" ::: "memory");  // tile t landed; 2 in flight
    } else {
      asm volatile("s_waitcnt vmcnt(0)" ::: "memory");
    }
    asm volatile("s_barrier" ::: "memory");

    bf16x8 bfr[JF];
    #pragma unroll
    for (int p = 0; p < 4; ++p) {
      const int ks = p >> 1, ih = p & 1;
      const int cb = ((((ks << 2) | quad) ^ (col & 7)) << 4);  // swizzled chunk byte
      bf16x8 af[4];
      #pragma unroll
      for (int i = 0; i < 4; ++i)
        af[i] = *(const bf16x8*)(bufR + abyte + (ih * 4 + i) * 2048 + cb);
      if (ih == 0) {
        #pragma unroll
        for (int j = 0; j < JF; ++j)
          bfr[j] = *(const bf16x8*)(bufR + bbyte + j * 2048 + cb);
      }
      if (hn && p < 3) {
        stage_one(2 + 2 * p, k0n, bufW);
        stage_one(3 + 2 * p, k0n, bufW);
      }
      asm volatile("s_waitcnt lgkmcnt(0)" ::: "memory");
      __builtin_amdgcn_s_setprio(1);
      #pragma unroll
      for (int i = 0; i < 4; ++i)
        #pragma unroll
        for (int j = 0; j < JF; ++j)
          acc[ih * 4 + i][j] = __builtin_amdgcn_mfma_f32_16x16x32_bf16(
              af[i], bfr[j], acc[ih * 4 + i][j], 0, 0, 0);
      __builtin_amdgcn_s_setprio(0);
      asm volatile("s_barrier" ::: "memory");
    }
    // last phase's barrier orders all bufR reads before next tile's writes to it
  }

  // Epilogue. C/D layout: col = lane&15, row = quad*4 + reg  [m89/m91 verified]
  #pragma unroll
  for (int i = 0; i < 8; ++i) {
    #pragma unroll
    for (int reg = 0; reg < 4; ++reg) {
      int r = m0 + wm * 128 + i * 16 + quad * 4 + reg;
      if (r < cnt) {
        unsigned short* hrow = Hout + (size_t)(base + r) * N + (n0 + wn * WN + col);
        if (MODE == 1) {
          #pragma unroll
          for (int j = 0; j < JF; ++j) {
            float v = acc[i][j][reg];
            float s = v / (1.f + __expf(-v));   // silu
            hrow[j * 16] = f2b(s);
          }
        } else {
          float wgt = rowwt[base + r];
          #pragma unroll
          for (int j = 0; j < JF; ++j)
            hrow[j * 16] = f2b(wgt * acc[i][j][reg]);
        }
      }
    }
  }
}

// ------- Combine: out[t] = Y[rowof[2t]] + Y[rowof[2t+1]] (weights pre-applied) -------
__global__ __launch_bounds__(256) void combine_k(
    const unsigned short* __restrict__ Y, const int* __restrict__ rowof,
    float* __restrict__ out)
{
  const int token = blockIdx.x;
  const int r1 = rowof[token * 2];
  const int r2 = rowof[token * 2 + 1];
  const int d4 = threadIdx.x;
  ushort4 a = *(const ushort4*)(Y + (size_t)r1 * D_MODEL + d4 * 4);
  ushort4 b = *(const ushort4*)(Y + (size_t)r2 * D_MODEL + d4 * 4);
  float4 o;
  o.x = b2f(a.x) + b2f(b.x);
  o.y = b2f(a.y) + b2f(b.y);
  o.z = b2f(a.z) + b2f(b.z);
  o.w = b2f(a.w) + b2f(b.w);
  *(float4*)(out + (size_t)token * D_MODEL + d4 * 4) = o;
}

extern "C" void kernel_launch(void* const* d_in, const int* in_sizes, int n_in,
                              void* d_out, int out_size, void* d_ws, size_t ws_size,
                              hipStream_t stream) {
  const float* x  = (const float*)d_in[0];
  const float* gw = (const float*)d_in[1];
  const float* w1 = (const float*)d_in[2];
  const float* w2 = (const float*)d_in[3];
  float* out = (float*)d_out;

  char* ws = (char*)d_ws;
  size_t off = 0;
  auto alloc = [&](size_t bytes) -> char* {
    char* p = ws + off; off += (bytes + 255) & ~(size_t)255; return p;
  };
  int*   ctrl    = (int*)alloc(1024);     // counts[8] | offsets[8] | tile_n | tiles
  int*   counts  = ctrl;
  int*   offsets = ctrl + 8;
  int*   tile_n  = ctrl + 16;
  int*   tile_e  = ctrl + 32;             // [MAXTILE]
  int*   tile_m0 = ctrl + 32 + MAXTILE;   // [MAXTILE]
  int*   eidx    = (int*)  alloc((size_t)NASSIGN * 4);
  float* ewt     = (float*)alloc((size_t)NASSIGN * 4);
  int*   rowtok  = (int*)  alloc((size_t)NASSIGN * 4);
  float* rowwt   = (float*)alloc((size_t)NASSIGN * 4);
  int*   rowof   = (int*)  alloc((size_t)NASSIGN * 4);
  unsigned short* Xe  = (unsigned short*)alloc((size_t)(NASSIGN + 256) * D_MODEL * 2);
  unsigned short* H   = (unsigned short*)alloc((size_t)(NASSIGN + 256) * D_FF * 2);
  unsigned short* Y   = (unsigned short*)alloc((size_t)(NASSIGN + 256) * D_MODEL * 2);
  unsigned short* w1t = (unsigned short*)alloc((size_t)N_EXP * D_MODEL * D_FF * 2);
  unsigned short* w2t = (unsigned short*)alloc((size_t)N_EXP * D_MODEL * D_FF * 2);

  prep_k<<<4096 + NTOK / 4, 256, 0, stream>>>(x, gw, w1, w2, w1t, w2t, eidx, ewt);
  scan_k<<<1, 1024, 0, stream>>>(eidx, ewt, counts, offsets, rowtok, rowwt, rowof,
                                 tile_e, tile_m0, tile_n);
  gather_k<<<NASSIGN, 256, 0, stream>>>(x, rowtok, Xe);

  // GEMM1: 40 M-tiles x 8 n-tiles = 320 blocks; GEMM2: 40 x 4 = 160 (single round)
  moe_gemm_k<D_MODEL, D_FF, 1><<<320, 512, 0, stream>>>(
      Xe, w1t, H, counts, offsets, rowwt, tile_e, tile_m0, tile_n);
  moe_gemm_k<D_FF, D_MODEL, 2><<<160, 512, 0, stream>>>(
      H, w2t, Y, counts, offsets, rowwt, tile_e, tile_m0, tile_n);
  combine_k<<<NTOK, 256, 0, stream>>>(Y, rowof, out);
}

// Round 20
// 321.161 us; speedup vs baseline: 1.1838x; 1.0375x over previous
//
#include <hip/hip_runtime.h>
#include <cstdint>
#include <cstddef>

#define D_MODEL 1024
#define D_FF    2048
#define N_EXP   8
#define NTOK    4096          // B*S
#define NASSIGN (NTOK * 2)    // top-2
#define MAXTILE 72            // 128-row tiles: sum ceil(cnt/128) <= 64+7 = 71

typedef __bf16 bf16_t;
typedef bf16_t bf16x8 __attribute__((ext_vector_type(8)));
typedef float  f32x4  __attribute__((ext_vector_type(4)));

typedef __attribute__((address_space(3))) void       lds_void;
typedef const __attribute__((address_space(1))) void gl_void;

__device__ __forceinline__ unsigned short f2b(float f) {
  union { float f; unsigned u; } v; v.f = f;
  unsigned u = v.u;
  unsigned r = (u + 0x7FFFu + ((u >> 16) & 1u)) >> 16;  // RNE
  return (unsigned short)r;
}
__device__ __forceinline__ float b2f(unsigned short b) {
  union { unsigned u; float f; } v; v.u = ((unsigned)b) << 16; return v.f;
}

// ---------------- Prep: w1/w2 transpose (128x64, glds LINEAR source) | router --------
// R19 measured: clean traffic (FETCH 74MB / WRITE 66MB), 78us @ 1.8 TB/s.  Kept.
__device__ __forceinline__ void transpose_tile_glin(
    const float* __restrict__ ein, unsigned short* __restrict__ eout,
    int R /*out stride*/, int C /*in cols*/, int r0, int c0,
    unsigned* T /*32KB*/, int tid)
{
  const int l = tid & 63;
  const int w = tid >> 6;        // wave 0..3

  #pragma unroll
  for (int n = 0; n < 8; ++n) {
    int g   = n * 4 + w;                       // group 0..31 = rows 4g..4g+3
    int row = g * 4 + (l >> 4);
    const float* src = ein + (size_t)(r0 + row) * C + c0 + ((l & 15) << 2);
    __builtin_amdgcn_global_load_lds((gl_void*)src,
        (lds_void*)((char*)T + g * 1024), 16, 0, 0);
  }
  __syncthreads();   // drains vmcnt, publishes LDS

  const int c  = tid >> 2;       // 0..63 : output row (input col)
  const int s4 = tid & 3;        // 32-row segment along r
  unsigned ow[16];
  #pragma unroll
  for (int j2 = 0; j2 < 16; ++j2) {
    int r = s4 * 32 + 2 * j2;
    float lo, hi;
    { union { unsigned u; float f; } v; v.u = T[r * 64 + c];       lo = v.f; }
    { union { unsigned u; float f; } v; v.u = T[(r + 1) * 64 + c]; hi = v.f; }
    ow[j2] = (unsigned)f2b(lo) | ((unsigned)f2b(hi) << 16);
  }
  uint4* dst = (uint4*)(eout + (size_t)(c0 + c) * R + r0 + s4 * 32);
  dst[0] = *(uint4*)&ow[0];
  dst[1] = *(uint4*)&ow[4];
  dst[2] = *(uint4*)&ow[8];
  dst[3] = *(uint4*)&ow[12];
}

__global__ __launch_bounds__(256) void prep_k(
    const float* __restrict__ x, const float* __restrict__ gw,
    const float* __restrict__ w1, const float* __restrict__ w2,
    unsigned short* __restrict__ w1t, unsigned short* __restrict__ w2t,
    int* __restrict__ eidx, float* __restrict__ ewt)
{
  __shared__ unsigned T[8192];   // 32 KB
  const int bid = blockIdx.x;
  const int tid = threadIdx.x;

  if (bid < 2048) {
    int e = bid >> 8, rem = bid & 255;
    int by = rem >> 5, bx = rem & 31;
    transpose_tile_glin(w1 + (size_t)e * D_MODEL * D_FF,
                        w1t + (size_t)e * D_MODEL * D_FF,
                        D_MODEL, D_FF, by * 128, bx * 64, T, tid);
    return;
  }
  if (bid < 4096) {
    int b = bid - 2048;
    int e = b >> 8, rem = b & 255;
    int by = rem >> 4, bx = rem & 15;
    transpose_tile_glin(w2 + (size_t)e * D_MODEL * D_FF,
                        w2t + (size_t)e * D_MODEL * D_FF,
                        D_FF, D_MODEL, by * 128, bx * 64, T, tid);
    return;
  }
  // router: fp32 logits, top-2, softmax
  const int rb = bid - 4096;
  const int wv = tid >> 6, lane = tid & 63;
  const int token = rb * 4 + wv;
  const float4* xr4 = (const float4*)(x + (size_t)token * D_MODEL);
  const float4* gw4 = (const float4*)gw;

  float acc[8] = {};
  #pragma unroll
  for (int it = 0; it < 4; ++it) {
    float4 xv = xr4[it * 64 + lane];
    int d0 = it * 256 + lane * 4;
    #pragma unroll
    for (int i = 0; i < 4; ++i) {
      int d = d0 + i;
      float4 g0 = gw4[d * 2];
      float4 g1 = gw4[d * 2 + 1];
      float xs = (i == 0) ? xv.x : (i == 1) ? xv.y : (i == 2) ? xv.z : xv.w;
      acc[0] += xs * g0.x; acc[1] += xs * g0.y;
      acc[2] += xs * g0.z; acc[3] += xs * g0.w;
      acc[4] += xs * g1.x; acc[5] += xs * g1.y;
      acc[6] += xs * g1.z; acc[7] += xs * g1.w;
    }
  }
  #pragma unroll
  for (int m = 1; m < 64; m <<= 1) {
    #pragma unroll
    for (int k = 0; k < 8; ++k) acc[k] += __shfl_xor(acc[k], m);
  }
  if (lane == 0) {
    int i1 = 0; float v1 = acc[0];
    #pragma unroll
    for (int k = 1; k < 8; ++k) if (acc[k] > v1) { v1 = acc[k]; i1 = k; }
    int i2 = -1; float v2 = -1e30f;
    #pragma unroll
    for (int k = 0; k < 8; ++k) if (k != i1 && acc[k] > v2) { v2 = acc[k]; i2 = k; }
    float t  = __expf(v2 - v1);
    float wa = 1.f / (1.f + t);
    float wb = t * wa;
    eidx[token * 2 + 0] = i1; eidx[token * 2 + 1] = i2;
    ewt [token * 2 + 0] = wa; ewt [token * 2 + 1] = wb;
  }
}

// ------- Scan: 1024 threads, 8 assigns/thread; emits 128-row tiles (R20) -------
__global__ __launch_bounds__(1024) void scan_k(
    const int* __restrict__ eidx, const float* __restrict__ ewt,
    int* __restrict__ counts, int* __restrict__ offsets,
    int* __restrict__ rowtok, float* __restrict__ rowwt, int* __restrict__ rowof,
    int* __restrict__ tile_e, int* __restrict__ tile_m0, int* __restrict__ tile_n)
{
  __shared__ int wtot[16][9];
  __shared__ int woff[16][9];
  __shared__ int soff[8];
  const int t = threadIdx.x, w = t >> 6, lane = t & 63;

  int4 a = ((const int4*)eidx)[t * 2];
  int4 b = ((const int4*)eidx)[t * 2 + 1];
  int my[8] = {a.x, a.y, a.z, a.w, b.x, b.y, b.z, b.w};
  int pre[8], local[8] = {};
  #pragma unroll
  for (int i = 0; i < 8; ++i) { pre[i] = local[my[i]]; local[my[i]]++; }

  int inc[8];
  #pragma unroll
  for (int e = 0; e < 8; ++e) inc[e] = local[e];
  #pragma unroll
  for (int d = 1; d < 64; d <<= 1) {
    #pragma unroll
    for (int e = 0; e < 8; ++e) {
      int v = __shfl_up(inc[e], d);
      if (lane >= d) inc[e] += v;
    }
  }
  if (lane == 63) {
    #pragma unroll
    for (int e = 0; e < 8; ++e) wtot[w][e] = inc[e];
  }
  __syncthreads();

  if (t < 8) {
    int e = t, run = 0;
    #pragma unroll
    for (int ww = 0; ww < 16; ++ww) { woff[ww][e] = run; run += wtot[ww][e]; }
    wtot[0][e] = run;
  }
  __syncthreads();

  if (t == 0) {
    int o = 0, tt = 0;
    for (int e = 0; e < 8; ++e) {
      int c = wtot[0][e];
      counts[e] = c;
      offsets[e] = o;
      soff[e] = o;
      int nt = (c + 127) >> 7;                       // 128-row tiles
      for (int i = 0; i < nt; ++i) { tile_e[tt] = e; tile_m0[tt] = i * 128; ++tt; }
      o += c;
    }
    tile_n[0] = tt;
  }
  __syncthreads();

  int base_[8];
  #pragma unroll
  for (int e = 0; e < 8; ++e) base_[e] = soff[e] + woff[w][e] + inc[e] - local[e];

  float4 wa4 = ((const float4*)ewt)[t * 2];
  float4 wb4 = ((const float4*)ewt)[t * 2 + 1];
  float wv[8] = {wa4.x, wa4.y, wa4.z, wa4.w, wb4.x, wb4.y, wb4.z, wb4.w};

  #pragma unroll
  for (int i = 0; i < 8; ++i) {
    int bb = t * 8 + i, e = my[i];
    int row = base_[e] + pre[i];
    rowtok[row] = bb >> 1;
    rowwt[row]  = wv[i];
    rowof[bb]   = row;
  }
}

// -------- Gather: block per row, x[token] -> bf16 Xe[row]. --------
__global__ __launch_bounds__(256) void gather_k(
    const float* __restrict__ x, const int* __restrict__ rowtok,
    unsigned short* __restrict__ Xe)
{
  const int row = blockIdx.x;
  const int token = rowtok[row];
  const float4* xr = (const float4*)(x + (size_t)token * D_MODEL);
  ushort4* dst = (ushort4*)(Xe + (size_t)row * D_MODEL);
  float4 v = xr[threadIdx.x];
  ushort4 o;
  o.x = f2b(v.x); o.y = f2b(v.y); o.z = f2b(v.z); o.w = f2b(v.w);
  dst[threadIdx.x] = o;
}

// -------- Segmented bf16 MFMA GEMM, 128x128 tile, BK=64, 4 waves (R20) --------
// Geometry rewrite for occupancy: 64 KB LDS -> 2 blocks/CU (cross-block overlap,
// m114); grids ~1088/544 blocks -> no idle CUs (was 160 blocks = 96 CUs idle).
// Same per-phase schedule as R11/R18: 4 phases {ds_read | stage-issues ->
// lgkmcnt(0) -> setprio MFMAx8 setprio -> barrier}; counted vmcnt(2) per K-tile;
// T2 swizzle via inverse-swizzled global src (row==col mod 8 preserved).
// MODE 1: Hout = bf16(silu(A.Bt^T))   MODE 2: Hout = bf16(rowwt * A.Bt^T)
template<int K, int N, int MODE>
__global__ __launch_bounds__(256) void moe_gemm_k(
    const unsigned short* __restrict__ A,
    const unsigned short* __restrict__ Bt,
    unsigned short* __restrict__ Hout,
    const int* __restrict__ counts, const int* __restrict__ offsets,
    const float* __restrict__ rowwt,
    const int* __restrict__ tile_e, const int* __restrict__ tile_m0,
    const int* __restrict__ tile_n)
{
  constexpr int BN    = 128;
  constexpr int RT    = 256;          // staged rows per K-tile (128 A + 128 B)
  constexpr int LOADS = 8;            // glds per thread per K-tile (32 rows each)
  constexpr int JF    = 4;            // j-fragments per wave (64 cols)
  constexpr int NT    = K / 64;       // K-tiles
  constexpr int NTN   = N / BN;       // n-tiles: G1=16, G2=8

  __shared__ char lds[2 * RT * 128];  // 64 KB -> 2 blocks/CU

  // XCD-aware swizzle: consecutive wg share the A-panel (same tile t_).
  const int nwg = gridDim.x;          // divisible by 8
  const int bid = blockIdx.x;
  const int wg  = (bid & 7) * (nwg >> 3) + (bid >> 3);
  const int t_  = wg / NTN;
  if (t_ >= tile_n[0]) return;
  const int e    = tile_e[t_];
  const int m0   = tile_m0[t_];
  const int n0   = (wg % NTN) * BN;
  const int cnt  = counts[e];
  const int base = offsets[e];

  const int tid  = threadIdx.x;
  const int l    = tid & 63;
  const int w    = tid >> 6;          // wave 0..3
  const int wm   = w >> 1;            // 0..1 : 64-row half
  const int wn   = w & 1;             // 0..1 : 64-col half
  const int col  = l & 15, quad = l >> 4;

  const unsigned short* Aseg = A + (size_t)base * K;
  const unsigned short* Bseg = Bt + (size_t)e * ((size_t)N * K);

  const int w8 = w * 8, l3 = l >> 3;
  const int ckst = ((l & 7) ^ l3) << 3;   // inverse-swizzled k-element offset

  auto stage_one = [&](int n, int k0s, char* bw) {
    // load n covers staged rows n*32 .. n*32+31 (A for n<4, else B)
    const unsigned short* src = (n < 4)
      ? Aseg + (size_t)(m0 + n * 32 + w8 + l3) * K + (k0s + ckst)
      : Bseg + (size_t)(n0 + (n - 4) * 32 + w8 + l3) * K + (k0s + ckst);
    __builtin_amdgcn_global_load_lds((gl_void*)src,
        (lds_void*)(bw + (n * 4 + w) * 1024), 16, 0, 0);
  };

  // prologue: stage K-tile 0 into buffer 0
  #pragma unroll
  for (int n = 0; n < LOADS; ++n) stage_one(n, 0, lds);

  const int abyte = (wm * 64 + col) * 128;           // A frag base row byte
  const int bbyte = (128 + wn * 64 + col) * 128;     // B frag base row byte

  f32x4 acc[4][JF] = {};

  for (int t = 0; t < NT; ++t) {
    char* bufR = lds + (t & 1) * (RT * 128);
    char* bufW = lds + ((t + 1) & 1) * (RT * 128);
    const int k0n = (t + 1) * 64;
    const bool hn = (t + 1 < NT);
    if (hn) {
      stage_one(0, k0n, bufW);
      stage_one(1, k0n, bufW);
      asm volatile("s_waitcnt vmcnt(2)" ::: "memory");  // tile t landed; 2 in flight
    } else {
      asm volatile("s_waitcnt vmcnt(0)" ::: "memory");
    }
    asm volatile("s_barrier" ::: "memory");

    bf16x8 bfr[JF];
    #pragma unroll
    for (int p = 0; p < 4; ++p) {
      const int ks = p >> 1, ih = p & 1;
      const int cb = ((((ks << 2) | quad) ^ (col & 7)) << 4);  // swizzled chunk byte
      bf16x8 af[2];
      #pragma unroll
      for (int i = 0; i < 2; ++i)
        af[i] = *(const bf16x8*)(bufR + abyte + (ih * 2 + i) * 2048 + cb);
      if (ih == 0) {
        #pragma unroll
        for (int j = 0; j < JF; ++j)
          bfr[j] = *(const bf16x8*)(bufR + bbyte + j * 2048 + cb);
      }
      if (hn && p < 3) {
        stage_one(2 + 2 * p, k0n, bufW);
        stage_one(3 + 2 * p, k0n, bufW);
      }
      asm volatile("s_waitcnt lgkmcnt(0)" ::: "memory");
      __builtin_amdgcn_s_setprio(1);
      #pragma unroll
      for (int i = 0; i < 2; ++i)
        #pragma unroll
        for (int j = 0; j < JF; ++j)
          acc[ih * 2 + i][j] = __builtin_amdgcn_mfma_f32_16x16x32_bf16(
              af[i], bfr[j], acc[ih * 2 + i][j], 0, 0, 0);
      __builtin_amdgcn_s_setprio(0);
      asm volatile("s_barrier" ::: "memory");
    }
    // last phase's barrier orders all bufR reads before next tile's writes to it
  }

  // Epilogue. C/D layout: col = lane&15, row = quad*4 + reg  [m89/m91 verified]
  #pragma unroll
  for (int i = 0; i < 4; ++i) {
    #pragma unroll
    for (int reg = 0; reg < 4; ++reg) {
      int r = m0 + wm * 64 + i * 16 + quad * 4 + reg;
      if (r < cnt) {
        unsigned short* hrow = Hout + (size_t)(base + r) * N + (n0 + wn * 64 + col);
        if (MODE == 1) {
          #pragma unroll
          for (int j = 0; j < JF; ++j) {
            float v = acc[i][j][reg];
            float s = v / (1.f + __expf(-v));   // silu
            hrow[j * 16] = f2b(s);
          }
        } else {
          float wgt = rowwt[base + r];
          #pragma unroll
          for (int j = 0; j < JF; ++j)
            hrow[j * 16] = f2b(wgt * acc[i][j][reg]);
        }
      }
    }
  }
}

// ------- Combine: out[t] = Y[rowof[2t]] + Y[rowof[2t+1]] (weights pre-applied) -------
__global__ __launch_bounds__(256) void combine_k(
    const unsigned short* __restrict__ Y, const int* __restrict__ rowof,
    float* __restrict__ out)
{
  const int token = blockIdx.x;
  const int r1 = rowof[token * 2];
  const int r2 = rowof[token * 2 + 1];
  const int d4 = threadIdx.x;
  ushort4 a = *(const ushort4*)(Y + (size_t)r1 * D_MODEL + d4 * 4);
  ushort4 b = *(const ushort4*)(Y + (size_t)r2 * D_MODEL + d4 * 4);
  float4 o;
  o.x = b2f(a.x) + b2f(b.x);
  o.y = b2f(a.y) + b2f(b.y);
  o.z = b2f(a.z) + b2f(b.z);
  o.w = b2f(a.w) + b2f(b.w);
  *(float4*)(out + (size_t)token * D_MODEL + d4 * 4) = o;
}

extern "C" void kernel_launch(void* const* d_in, const int* in_sizes, int n_in,
                              void* d_out, int out_size, void* d_ws, size_t ws_size,
                              hipStream_t stream) {
  const float* x  = (const float*)d_in[0];
  const float* gw = (const float*)d_in[1];
  const float* w1 = (const float*)d_in[2];
  const float* w2 = (const float*)d_in[3];
  float* out = (float*)d_out;

  char* ws = (char*)d_ws;
  size_t off = 0;
  auto alloc = [&](size_t bytes) -> char* {
    char* p = ws + off; off += (bytes + 255) & ~(size_t)255; return p;
  };
  int*   ctrl    = (int*)alloc(1024);     // counts[8] | offsets[8] | tile_n | tiles
  int*   counts  = ctrl;
  int*   offsets = ctrl + 8;
  int*   tile_n  = ctrl + 16;
  int*   tile_e  = ctrl + 32;             // [MAXTILE]
  int*   tile_m0 = ctrl + 32 + MAXTILE;   // [MAXTILE]
  int*   eidx    = (int*)  alloc((size_t)NASSIGN * 4);
  float* ewt     = (float*)alloc((size_t)NASSIGN * 4);
  int*   rowtok  = (int*)  alloc((size_t)NASSIGN * 4);
  float* rowwt   = (float*)alloc((size_t)NASSIGN * 4);
  int*   rowof   = (int*)  alloc((size_t)NASSIGN * 4);
  unsigned short* Xe  = (unsigned short*)alloc((size_t)(NASSIGN + 256) * D_MODEL * 2);
  unsigned short* H   = (unsigned short*)alloc((size_t)(NASSIGN + 256) * D_FF * 2);
  unsigned short* Y   = (unsigned short*)alloc((size_t)(NASSIGN + 256) * D_MODEL * 2);
  unsigned short* w1t = (unsigned short*)alloc((size_t)N_EXP * D_MODEL * D_FF * 2);
  unsigned short* w2t = (unsigned short*)alloc((size_t)N_EXP * D_MODEL * D_FF * 2);

  prep_k<<<4096 + NTOK / 4, 256, 0, stream>>>(x, gw, w1, w2, w1t, w2t, eidx, ewt);
  scan_k<<<1, 1024, 0, stream>>>(eidx, ewt, counts, offsets, rowtok, rowwt, rowof,
                                 tile_e, tile_m0, tile_n);
  gather_k<<<NASSIGN, 256, 0, stream>>>(x, rowtok, Xe);

  // 72 M-tiles max; GEMM1: 72x16 = 1152 blocks; GEMM2: 72x8 = 576 (both %8==0)
  moe_gemm_k<D_MODEL, D_FF, 1><<<1152, 256, 0, stream>>>(
      Xe, w1t, H, counts, offsets, rowwt, tile_e, tile_m0, tile_n);
  moe_gemm_k<D_FF, D_MODEL, 2><<<576, 256, 0, stream>>>(
      H, w2t, Y, counts, offsets, rowwt, tile_e, tile_m0, tile_n);
  combine_k<<<NTOK, 256, 0, stream>>>(Y, rowof, out);
}